// Round 9
// baseline (2641.590 us; speedup 1.0000x reference)
//
#include <hip/hip_runtime.h>

typedef unsigned short u16;
typedef unsigned int u32;
typedef unsigned long long u64;
typedef short v8s __attribute__((ext_vector_type(8)));
typedef float v4f __attribute__((ext_vector_type(4)));

// T=256, B=64, NIN=H=512, NOUT=512, 4H=2048, T*B=16384
#define TT 256
#define BB 64
#define HH 512
#define G4 2048
#define MTB 16384

static __device__ __forceinline__ float bf2f(u16 u) {
    u32 x = ((u32)u) << 16;
    union { u32 i; float f; } c; c.i = x; return c.f;
}
static __device__ __forceinline__ u16 f2bf(float f) {
    union { float f; u32 i; } c; c.f = f;
    u32 u = c.i;
    u += 0x7fffu + ((u >> 16) & 1u);   // RNE
    return (u16)(u >> 16);
}

__global__ __launch_bounds__(256) void cvt_bf16(const float* __restrict__ src,
                                                u16* __restrict__ dst, int n) {
    int i = blockIdx.x * blockDim.x + threadIdx.x;
    int stride = gridDim.x * blockDim.x;
    for (int j = i * 4; j < n; j += stride * 4) {
        float4 v = *reinterpret_cast<const float4*>(src + j);
        ushort4 o;
        o.x = f2bf(v.x); o.y = f2bf(v.y); o.z = f2bf(v.z); o.w = f2bf(v.w);
        *reinterpret_cast<ushort4*>(dst + j) = o;
    }
}

// C[M][N] = A[M][K] * B[N][K]^T (+ bias).  A,B bf16 K-contiguous; 128x128 tile, BK=64,
// 4 waves in 2x2, each wave 64x64 = 4x4 16x16x32 fragments. M,N,K multiples of 128 assumed.
template<bool OUT_BF16, bool BIAS_M>
__global__ __launch_bounds__(256) void gemm_bt(const u16* __restrict__ A,
                                               const u16* __restrict__ Bm,
                                               void* __restrict__ Cv,
                                               const float* __restrict__ bias1,
                                               const float* __restrict__ bias2,
                                               int M, int N, int K) {
    __shared__ u16 lds_a[128 * 64];
    __shared__ u16 lds_b[128 * 64];
    const int tid = threadIdx.x, lane = tid & 63;
    const int m0 = blockIdx.y * 128, n0 = blockIdx.x * 128;
    const int wid = tid >> 6, wm = wid >> 1, wn = wid & 1;
    v4f acc[4][4] = {};

    const int srow  = tid >> 3;        // 0..31: row within 32-row staging stripe
    const int skoff = (tid & 7) * 8;   // bf16 elements within 64-wide k
    const u16* Ag = A + (size_t)(m0 + srow) * K + skoff;
    const u16* Bg = Bm + (size_t)(n0 + srow) * K + skoff;
    u16* la = lds_a + srow * 64 + skoff;
    u16* lb = lds_b + srow * 64 + skoff;

    for (int k0 = 0; k0 < K; k0 += 64) {
        #pragma unroll
        for (int q = 0; q < 4; ++q) {
            *reinterpret_cast<v8s*>(la + q * 32 * 64) =
                *reinterpret_cast<const v8s*>(Ag + (size_t)q * 32 * K + k0);
            *reinterpret_cast<v8s*>(lb + q * 32 * 64) =
                *reinterpret_cast<const v8s*>(Bg + (size_t)q * 32 * K + k0);
        }
        __syncthreads();
        #pragma unroll
        for (int kk = 0; kk < 2; ++kk) {
            v8s af[4], bfr[4];
            #pragma unroll
            for (int i = 0; i < 4; ++i)
                af[i] = *reinterpret_cast<const v8s*>(
                    lds_a + (wm * 64 + i * 16 + (lane & 15)) * 64 + kk * 32 + (lane >> 4) * 8);
            #pragma unroll
            for (int i = 0; i < 4; ++i)
                bfr[i] = *reinterpret_cast<const v8s*>(
                    lds_b + (wn * 64 + i * 16 + (lane & 15)) * 64 + kk * 32 + (lane >> 4) * 8);
            #pragma unroll
            for (int i = 0; i < 4; ++i)
                #pragma unroll
                for (int j = 0; j < 4; ++j)
                    acc[i][j] = __builtin_amdgcn_mfma_f32_16x16x32_bf16(af[i], bfr[j], acc[i][j], 0, 0, 0);
        }
        __syncthreads();
    }
    // epilogue: D col = lane&15 (n), row = (lane>>4)*4 + reg (m)
    #pragma unroll
    for (int i = 0; i < 4; ++i) {
        #pragma unroll
        for (int j = 0; j < 4; ++j) {
            #pragma unroll
            for (int r = 0; r < 4; ++r) {
                int m = m0 + wm * 64 + i * 16 + (lane >> 4) * 4 + r;
                int n = n0 + wn * 64 + j * 16 + (lane & 15);
                float v = acc[i][j][r];
                if (BIAS_M) { v += bias1[m]; if (bias2) v += bias2[m]; }
                else        { v += bias1[n]; }
                if (OUT_BF16) ((u16*)Cv)[(size_t)m * N + n] = f2bf(v);
                else          ((float*)Cv)[(size_t)m * N + n] = v;
            }
        }
    }
}

static __device__ __forceinline__ float sigm(float x) { return 1.f / (1.f + __expf(-x)); }
static __device__ __forceinline__ float tanh_(float x) { return 2.f / (1.f + __expf(-2.f * x)) - 1.f; }

// Persistent bidirectional LSTM recurrence — DIRECTION-FUSED blocks.
// R8 lesson: flag publish -> remote detect is ~4-5us (the dominant per-step term);
// R6's xg shadow was free because it OVERLAPPED that window. So: one block now
// handles BOTH directions (f-phase then b-phase per iteration). Each direction's
// propagation window is hidden under the other direction's compute phase; per
// iteration (2 step-dirs) the cost is max(propagation, 2*phase) instead of
// 2*(propagation + phase). Publish uses atomic_fetch_add (executes at the IC
// near-memory atomic units -> value immediately at the coherence point, no
// dirty-L2 probe path).
// 64 blocks x 256 threads: blockIdx.x = cg (8 j-columns), both dirs. Wave nf owns
// batch rows b = nf*16..+15. Per dir: 32 gate-rows = 2 A-frags of 16 rows packed as
// (jj = row>>2, G = row&3) so after MFMA lane (lk,lrow) holds acc[f][r] = gate G=r
// at j = cg*8 + f*4 + lk, b = nf*16+lrow — all 4 gates in-lane, c in 2 regs/dir.
// Weights: [d][f][kk][lane]*16B pre-swizzled fragments, 64 KB static LDS.
__global__ __launch_bounds__(256, 1) void lstm_persist(
    const u16* __restrict__ w_hh,        // [2][2048][512]
    const u16* __restrict__ xgT,         // [2][2048][16384]  col = t*64+b
    u16* __restrict__ h_all,             // [256*64][1024]
    unsigned* __restrict__ flags)        // [2][4][64] step counters
{
    __shared__ u16 wlds[2 * 2 * 16 * 64 * 8];    // [d][frag][kk][lane][8] = 64 KB
    const int cg = blockIdx.x;                   // 0..63, 8 j-columns each
    const int lane = threadIdx.x & 63, nf = threadIdx.x >> 6;
    const int lrow = lane & 15, lk = lane >> 4;
    const int b = nf * 16 + lrow;                // this lane's batch column

    // ---- stage A fragments: wave nf fills (d = nf>>1, f = nf&1) ----
    {
        const int d0 = nf >> 1, f0 = nf & 1;
        const int jj = lrow >> 2, G = lrow & 3;  // A row lrow -> (jj,G)
        const u16* wrow = w_hh + ((size_t)d0 * G4 + G * HH + cg * 8 + f0 * 4 + jj) * HH + lk * 8;
        #pragma unroll
        for (int kk = 0; kk < 16; ++kk)
            *reinterpret_cast<v8s*>(&wlds[(((d0 * 2 + f0) * 16 + kk) * 64 + lane) * 8]) =
                *reinterpret_cast<const v8s*>(wrow + kk * 32);
    }
    __syncthreads();

    float c[2][2] = {{0.f, 0.f}, {0.f, 0.f}};    // [dir][frag]
    float xgp[2][8];                              // [dir][f*4+G] prefetched gate inputs

    // xg for step 0, both dirs
    #pragma unroll
    for (int d = 0; d < 2; ++d) {
        const int t0 = d ? (TT - 1) : 0;
        const u16* base = xgT + (size_t)d * G4 * MTB + (size_t)t0 * BB + b;
        #pragma unroll
        for (int f = 0; f < 2; ++f)
            #pragma unroll
            for (int G = 0; G < 4; ++G)
                xgp[d][f * 4 + G] = bf2f(base[(size_t)(G * HH + cg * 8 + f * 4 + lk) * MTB]);
    }

    for (int s = 0; s < TT; ++s) {
        #pragma unroll
        for (int d = 0; d < 2; ++d) {
            const int t = d ? (TT - 1 - s) : s;
            v4f acc[2] = {};
            if (s > 0) {
                // ---- poll this dir's 64 producer flags (lane l <-> cg' l) ----
                unsigned* fl = flags + (d * 4 + nf) * 64;
                const unsigned tgt = (unsigned)s;
                while (true) {
                    unsigned fv = __hip_atomic_load(&fl[lane],
                                                    __ATOMIC_RELAXED, __HIP_MEMORY_SCOPE_AGENT);
                    if (__all((int)(fv >= tgt))) break;
                }
                asm volatile("" ::: "memory");
                // ---- h[tprev] B-fragments (16 x 16B, agent-coherent) ----
                const int tprev = d ? (t + 1) : (t - 1);
                const u16* hp = h_all + ((size_t)tprev * BB + b) * 1024 + d * HH + lk * 8;
                v8s bh[16];
                #pragma unroll
                for (int kk = 0; kk < 16; ++kk) {
                    union { u64 w[2]; v8s v; } u;
                    const u16* p = hp + kk * 32;
                    u.w[0] = __hip_atomic_load((const u64*)p,
                                               __ATOMIC_RELAXED, __HIP_MEMORY_SCOPE_AGENT);
                    u.w[1] = __hip_atomic_load((const u64*)(p + 4),
                                               __ATOMIC_RELAXED, __HIP_MEMORY_SCOPE_AGENT);
                    bh[kk] = u.v;
                }
                // ---- MFMA: 2 frags x 16 kk, weights from LDS ----
                #pragma unroll
                for (int kk = 0; kk < 16; ++kk)
                    #pragma unroll
                    for (int f = 0; f < 2; ++f) {
                        v8s af = *reinterpret_cast<const v8s*>(
                            &wlds[(((d * 2 + f) * 16 + kk) * 64 + lane) * 8]);
                        acc[f] = __builtin_amdgcn_mfma_f32_16x16x32_bf16(af, bh[kk], acc[f], 0, 0, 0);
                    }
            }
            // ---- gates + state update: acc[f][r] = gate G=r at j=cg*8+f*4+lk ----
            #pragma unroll
            for (int f = 0; f < 2; ++f) {
                float pi = acc[f][0] + xgp[d][f * 4 + 0];
                float pf = acc[f][1] + xgp[d][f * 4 + 1];
                float pg = acc[f][2] + xgp[d][f * 4 + 2];
                float po = acc[f][3] + xgp[d][f * 4 + 3];
                float iv = sigm(pi), fv = sigm(pf), gv = tanh_(pg), ov = sigm(po);
                float cc = fv * c[d][f] + iv * gv;
                c[d][f] = cc;
                u16 hv = f2bf(ov * tanh_(cc));
                __hip_atomic_store(
                    h_all + ((size_t)t * BB + b) * 1024 + d * HH + cg * 8 + f * 4 + lk,
                    hv, __ATOMIC_RELAXED, __HIP_MEMORY_SCOPE_AGENT);
            }
            // drain h stores, publish via near-memory RMW (value lands AT the IC)
            asm volatile("s_waitcnt vmcnt(0)" ::: "memory");
            if (lane == 0)
                __hip_atomic_fetch_add(&flags[(d * 4 + nf) * 64 + cg], 1u,
                                       __ATOMIC_RELAXED, __HIP_MEMORY_SCOPE_AGENT);
            // ---- prefetch next step's xg for THIS dir (shadow overlaps propagation) ----
            if (s + 1 < TT) {
                const int tn = d ? (TT - 2 - s) : (s + 1);
                const u16* base = xgT + (size_t)d * G4 * MTB + (size_t)tn * BB + b;
                #pragma unroll
                for (int f = 0; f < 2; ++f)
                    #pragma unroll
                    for (int G = 0; G < 4; ++G)
                        xgp[d][f * 4 + G] = bf2f(base[(size_t)(G * HH + cg * 8 + f * 4 + lk) * MTB]);
            }
        }
    }
}

extern "C" void kernel_launch(void* const* d_in, const int* in_sizes, int n_in,
                              void* d_out, int out_size, void* d_ws, size_t ws_size,
                              hipStream_t stream) {
    const float* x    = (const float*)d_in[0];
    const float* wihf = (const float*)d_in[1];
    const float* whhf = (const float*)d_in[2];
    const float* bihf = (const float*)d_in[3];
    const float* bhhf = (const float*)d_in[4];
    const float* wihb = (const float*)d_in[5];
    const float* whhb = (const float*)d_in[6];
    const float* bihb = (const float*)d_in[7];
    const float* bhhb = (const float*)d_in[8];
    const float* fcw  = (const float*)d_in[9];
    const float* fcb  = (const float*)d_in[10];

    char* ws = (char*)d_ws;
    size_t off = 0;
    auto alloc = [&](size_t bytes) {
        off = (off + 255) & ~(size_t)255;
        char* p = ws + off; off += bytes; return p;
    };
    u16* x_bf    = (u16*)alloc((size_t)MTB * 512 * 2);        // 16.8 MB
    u16* wih_bf  = (u16*)alloc((size_t)2 * G4 * 512 * 2);     // 4.2 MB
    u16* whh_bf  = (u16*)alloc((size_t)2 * G4 * 512 * 2);     // 4.2 MB
    u16* fcw_bf  = (u16*)alloc((size_t)512 * 1024 * 2);       // 1.0 MB
    u16* xgT     = (u16*)alloc((size_t)2 * G4 * MTB * 2);     // 134.2 MB
    u16* h_all   = (u16*)alloc((size_t)MTB * 1024 * 2);       // 33.6 MB
    unsigned* flags = (unsigned*)alloc(2 * 4 * 64 * sizeof(unsigned));
    (void)ws_size;

    // ---- convert inputs to bf16 ----
    cvt_bf16<<<1024, 256, 0, stream>>>(x, x_bf, MTB * 512);
    cvt_bf16<<<256, 256, 0, stream>>>(wihf, wih_bf, G4 * 512);
    cvt_bf16<<<256, 256, 0, stream>>>(wihb, wih_bf + (size_t)G4 * 512, G4 * 512);
    cvt_bf16<<<256, 256, 0, stream>>>(whhf, whh_bf, G4 * 512);
    cvt_bf16<<<256, 256, 0, stream>>>(whhb, whh_bf + (size_t)G4 * 512, G4 * 512);
    cvt_bf16<<<128, 256, 0, stream>>>(fcw, fcw_bf, 512 * 1024);

    // ---- phase 1: xgT[d] = w_ih[d] @ x^T + (b_ih + b_hh), bf16 out, gate-major ----
    gemm_bt<true, true><<<dim3(MTB / 128, G4 / 128), 256, 0, stream>>>(
        wih_bf, x_bf, xgT, bihf, bhhf, G4, MTB, 512);
    gemm_bt<true, true><<<dim3(MTB / 128, G4 / 128), 256, 0, stream>>>(
        wih_bf + (size_t)G4 * 512, x_bf, xgT + (size_t)G4 * MTB, bihb, bhhb, G4, MTB, 512);

    // ---- phase 2: persistent recurrence, direction-fused, RMW flag publish ----
    hipMemsetAsync(flags, 0, 2 * 4 * 64 * sizeof(unsigned), stream);
    lstm_persist<<<64, 256, 0, stream>>>(whh_bf, xgT, h_all, flags);

    // ---- phase 3: out = h_all @ fc_w^T + fc_b, fp32 out ----
    gemm_bt<false, false><<<dim3(512 / 128, MTB / 128), 256, 0, stream>>>(
        h_all, fcw_bf, d_out, fcb, nullptr, MTB, 512, 1024);
}

// Round 10
// 2606.372 us; speedup vs baseline: 1.0135x; 1.0135x over previous
//
#include <hip/hip_runtime.h>

typedef unsigned short u16;
typedef unsigned int u32;
typedef unsigned long long u64;
typedef short v8s __attribute__((ext_vector_type(8)));
typedef float v4f __attribute__((ext_vector_type(4)));

// T=256, B=64, NIN=H=512, NOUT=512, 4H=2048, T*B=16384
#define TT 256
#define BB 64
#define HH 512
#define G4 2048
#define MTB 16384

static __device__ __forceinline__ float bf2f(u16 u) {
    u32 x = ((u32)u) << 16;
    union { u32 i; float f; } c; c.i = x; return c.f;
}
static __device__ __forceinline__ u16 f2bf(float f) {
    union { float f; u32 i; } c; c.f = f;
    u32 u = c.i;
    u += 0x7fffu + ((u >> 16) & 1u);   // RNE
    return (u16)(u >> 16);
}

__global__ __launch_bounds__(256) void cvt_bf16(const float* __restrict__ src,
                                                u16* __restrict__ dst, int n) {
    int i = blockIdx.x * blockDim.x + threadIdx.x;
    int stride = gridDim.x * blockDim.x;
    for (int j = i * 4; j < n; j += stride * 4) {
        float4 v = *reinterpret_cast<const float4*>(src + j);
        ushort4 o;
        o.x = f2bf(v.x); o.y = f2bf(v.y); o.z = f2bf(v.z); o.w = f2bf(v.w);
        *reinterpret_cast<ushort4*>(dst + j) = o;
    }
}

// C[M][N] = A[M][K] * B[N][K]^T (+ bias).  A,B bf16 K-contiguous; 128x128 tile, BK=64,
// 4 waves in 2x2, each wave 64x64 = 4x4 16x16x32 fragments. M,N,K multiples of 128 assumed.
template<bool OUT_BF16, bool BIAS_M>
__global__ __launch_bounds__(256) void gemm_bt(const u16* __restrict__ A,
                                               const u16* __restrict__ Bm,
                                               void* __restrict__ Cv,
                                               const float* __restrict__ bias1,
                                               const float* __restrict__ bias2,
                                               int M, int N, int K) {
    __shared__ u16 lds_a[128 * 64];
    __shared__ u16 lds_b[128 * 64];
    const int tid = threadIdx.x, lane = tid & 63;
    const int m0 = blockIdx.y * 128, n0 = blockIdx.x * 128;
    const int wid = tid >> 6, wm = wid >> 1, wn = wid & 1;
    v4f acc[4][4] = {};

    const int srow  = tid >> 3;        // 0..31: row within 32-row staging stripe
    const int skoff = (tid & 7) * 8;   // bf16 elements within 64-wide k
    const u16* Ag = A + (size_t)(m0 + srow) * K + skoff;
    const u16* Bg = Bm + (size_t)(n0 + srow) * K + skoff;
    u16* la = lds_a + srow * 64 + skoff;
    u16* lb = lds_b + srow * 64 + skoff;

    for (int k0 = 0; k0 < K; k0 += 64) {
        #pragma unroll
        for (int q = 0; q < 4; ++q) {
            *reinterpret_cast<v8s*>(la + q * 32 * 64) =
                *reinterpret_cast<const v8s*>(Ag + (size_t)q * 32 * K + k0);
            *reinterpret_cast<v8s*>(lb + q * 32 * 64) =
                *reinterpret_cast<const v8s*>(Bg + (size_t)q * 32 * K + k0);
        }
        __syncthreads();
        #pragma unroll
        for (int kk = 0; kk < 2; ++kk) {
            v8s af[4], bfr[4];
            #pragma unroll
            for (int i = 0; i < 4; ++i)
                af[i] = *reinterpret_cast<const v8s*>(
                    lds_a + (wm * 64 + i * 16 + (lane & 15)) * 64 + kk * 32 + (lane >> 4) * 8);
            #pragma unroll
            for (int i = 0; i < 4; ++i)
                bfr[i] = *reinterpret_cast<const v8s*>(
                    lds_b + (wn * 64 + i * 16 + (lane & 15)) * 64 + kk * 32 + (lane >> 4) * 8);
            #pragma unroll
            for (int i = 0; i < 4; ++i)
                #pragma unroll
                for (int j = 0; j < 4; ++j)
                    acc[i][j] = __builtin_amdgcn_mfma_f32_16x16x32_bf16(af[i], bfr[j], acc[i][j], 0, 0, 0);
        }
        __syncthreads();
    }
    // epilogue: D col = lane&15 (n), row = (lane>>4)*4 + reg (m)
    #pragma unroll
    for (int i = 0; i < 4; ++i) {
        #pragma unroll
        for (int j = 0; j < 4; ++j) {
            #pragma unroll
            for (int r = 0; r < 4; ++r) {
                int m = m0 + wm * 64 + i * 16 + (lane >> 4) * 4 + r;
                int n = n0 + wn * 64 + j * 16 + (lane & 15);
                float v = acc[i][j][r];
                if (BIAS_M) { v += bias1[m]; if (bias2) v += bias2[m]; }
                else        { v += bias1[n]; }
                if (OUT_BF16) ((u16*)Cv)[(size_t)m * N + n] = f2bf(v);
                else          ((float*)Cv)[(size_t)m * N + n] = v;
            }
        }
    }
}

static __device__ __forceinline__ float sigm(float x) { return 1.f / (1.f + __expf(-x)); }
static __device__ __forceinline__ float tanh_(float x) { return 2.f / (1.f + __expf(-2.f * x)) - 1.f; }

// Persistent bidirectional LSTM recurrence — DIRECTION-FUSED blocks.
// R8 lesson: flag publish -> remote detect is ~4-5us (the dominant per-step term);
// R6's xg shadow was free because it OVERLAPPED that window. So: one block now
// handles BOTH directions (f-phase then b-phase per iteration). Each direction's
// propagation window is hidden under the other direction's compute phase; per
// iteration (2 step-dirs) the cost is max(propagation, 2*phase) instead of
// 2*(propagation + phase). Publish uses atomic_fetch_add (executes at the IC
// near-memory atomic units -> value immediately at the coherence point, no
// dirty-L2 probe path).
// 64 blocks x 256 threads: blockIdx.x = cg (8 j-columns), both dirs. Wave nf owns
// batch rows b = nf*16..+15. Per dir: 32 gate-rows = 2 A-frags of 16 rows packed as
// (jj = row>>2, G = row&3) so after MFMA lane (lk,lrow) holds acc[f][r] = gate G=r
// at j = cg*8 + f*4 + lk, b = nf*16+lrow — all 4 gates in-lane, c in 2 regs/dir.
// Weights: [d][f][kk][lane]*16B pre-swizzled fragments, 64 KB static LDS.
__global__ __launch_bounds__(256, 1) void lstm_persist(
    const u16* __restrict__ w_hh,        // [2][2048][512]
    const u16* __restrict__ xgT,         // [2][2048][16384]  col = t*64+b
    u16* __restrict__ h_all,             // [256*64][1024]
    unsigned* __restrict__ flags)        // [2][4][64] step counters
{
    __shared__ u16 wlds[2 * 2 * 16 * 64 * 8];    // [d][frag][kk][lane][8] = 64 KB
    const int cg = blockIdx.x;                   // 0..63, 8 j-columns each
    const int lane = threadIdx.x & 63, nf = threadIdx.x >> 6;
    const int lrow = lane & 15, lk = lane >> 4;
    const int b = nf * 16 + lrow;                // this lane's batch column

    // ---- stage A fragments: wave nf fills (d = nf>>1, f = nf&1) ----
    {
        const int d0 = nf >> 1, f0 = nf & 1;
        const int jj = lrow >> 2, G = lrow & 3;  // A row lrow -> (jj,G)
        const u16* wrow = w_hh + ((size_t)d0 * G4 + G * HH + cg * 8 + f0 * 4 + jj) * HH + lk * 8;
        #pragma unroll
        for (int kk = 0; kk < 16; ++kk)
            *reinterpret_cast<v8s*>(&wlds[(((d0 * 2 + f0) * 16 + kk) * 64 + lane) * 8]) =
                *reinterpret_cast<const v8s*>(wrow + kk * 32);
    }
    __syncthreads();

    float c[2][2] = {{0.f, 0.f}, {0.f, 0.f}};    // [dir][frag]
    float xgp[2][8];                              // [dir][f*4+G] prefetched gate inputs

    // xg for step 0, both dirs
    #pragma unroll
    for (int d = 0; d < 2; ++d) {
        const int t0 = d ? (TT - 1) : 0;
        const u16* base = xgT + (size_t)d * G4 * MTB + (size_t)t0 * BB + b;
        #pragma unroll
        for (int f = 0; f < 2; ++f)
            #pragma unroll
            for (int G = 0; G < 4; ++G)
                xgp[d][f * 4 + G] = bf2f(base[(size_t)(G * HH + cg * 8 + f * 4 + lk) * MTB]);
    }

    for (int s = 0; s < TT; ++s) {
        #pragma unroll
        for (int d = 0; d < 2; ++d) {
            const int t = d ? (TT - 1 - s) : s;
            v4f acc[2] = {};
            if (s > 0) {
                // ---- poll this dir's 64 producer flags (lane l <-> cg' l) ----
                unsigned* fl = flags + (d * 4 + nf) * 64;
                const unsigned tgt = (unsigned)s;
                while (true) {
                    unsigned fv = __hip_atomic_load(&fl[lane],
                                                    __ATOMIC_RELAXED, __HIP_MEMORY_SCOPE_AGENT);
                    if (__all((int)(fv >= tgt))) break;
                }
                asm volatile("" ::: "memory");
                // ---- h[tprev] B-fragments (16 x 16B, agent-coherent) ----
                const int tprev = d ? (t + 1) : (t - 1);
                const u16* hp = h_all + ((size_t)tprev * BB + b) * 1024 + d * HH + lk * 8;
                v8s bh[16];
                #pragma unroll
                for (int kk = 0; kk < 16; ++kk) {
                    union { u64 w[2]; v8s v; } u;
                    const u16* p = hp + kk * 32;
                    u.w[0] = __hip_atomic_load((const u64*)p,
                                               __ATOMIC_RELAXED, __HIP_MEMORY_SCOPE_AGENT);
                    u.w[1] = __hip_atomic_load((const u64*)(p + 4),
                                               __ATOMIC_RELAXED, __HIP_MEMORY_SCOPE_AGENT);
                    bh[kk] = u.v;
                }
                // ---- MFMA: 2 frags x 16 kk, weights from LDS ----
                #pragma unroll
                for (int kk = 0; kk < 16; ++kk)
                    #pragma unroll
                    for (int f = 0; f < 2; ++f) {
                        v8s af = *reinterpret_cast<const v8s*>(
                            &wlds[(((d * 2 + f) * 16 + kk) * 64 + lane) * 8]);
                        acc[f] = __builtin_amdgcn_mfma_f32_16x16x32_bf16(af, bh[kk], acc[f], 0, 0, 0);
                    }
            }
            // ---- gates + state update: acc[f][r] = gate G=r at j=cg*8+f*4+lk ----
            #pragma unroll
            for (int f = 0; f < 2; ++f) {
                float pi = acc[f][0] + xgp[d][f * 4 + 0];
                float pf = acc[f][1] + xgp[d][f * 4 + 1];
                float pg = acc[f][2] + xgp[d][f * 4 + 2];
                float po = acc[f][3] + xgp[d][f * 4 + 3];
                float iv = sigm(pi), fv = sigm(pf), gv = tanh_(pg), ov = sigm(po);
                float cc = fv * c[d][f] + iv * gv;
                c[d][f] = cc;
                u16 hv = f2bf(ov * tanh_(cc));
                __hip_atomic_store(
                    h_all + ((size_t)t * BB + b) * 1024 + d * HH + cg * 8 + f * 4 + lk,
                    hv, __ATOMIC_RELAXED, __HIP_MEMORY_SCOPE_AGENT);
            }
            // drain h stores, publish via near-memory RMW (value lands AT the IC)
            asm volatile("s_waitcnt vmcnt(0)" ::: "memory");
            if (lane == 0)
                __hip_atomic_fetch_add(&flags[(d * 4 + nf) * 64 + cg], 1u,
                                       __ATOMIC_RELAXED, __HIP_MEMORY_SCOPE_AGENT);
            // ---- prefetch next step's xg for THIS dir (shadow overlaps propagation) ----
            if (s + 1 < TT) {
                const int tn = d ? (TT - 2 - s) : (s + 1);
                const u16* base = xgT + (size_t)d * G4 * MTB + (size_t)tn * BB + b;
                #pragma unroll
                for (int f = 0; f < 2; ++f)
                    #pragma unroll
                    for (int G = 0; G < 4; ++G)
                        xgp[d][f * 4 + G] = bf2f(base[(size_t)(G * HH + cg * 8 + f * 4 + lk) * MTB]);
            }
        }
    }
}

extern "C" void kernel_launch(void* const* d_in, const int* in_sizes, int n_in,
                              void* d_out, int out_size, void* d_ws, size_t ws_size,
                              hipStream_t stream) {
    const float* x    = (const float*)d_in[0];
    const float* wihf = (const float*)d_in[1];
    const float* whhf = (const float*)d_in[2];
    const float* bihf = (const float*)d_in[3];
    const float* bhhf = (const float*)d_in[4];
    const float* wihb = (const float*)d_in[5];
    const float* whhb = (const float*)d_in[6];
    const float* bihb = (const float*)d_in[7];
    const float* bhhb = (const float*)d_in[8];
    const float* fcw  = (const float*)d_in[9];
    const float* fcb  = (const float*)d_in[10];

    char* ws = (char*)d_ws;
    size_t off = 0;
    auto alloc = [&](size_t bytes) {
        off = (off + 255) & ~(size_t)255;
        char* p = ws + off; off += bytes; return p;
    };
    u16* x_bf    = (u16*)alloc((size_t)MTB * 512 * 2);        // 16.8 MB
    u16* wih_bf  = (u16*)alloc((size_t)2 * G4 * 512 * 2);     // 4.2 MB
    u16* whh_bf  = (u16*)alloc((size_t)2 * G4 * 512 * 2);     // 4.2 MB
    u16* fcw_bf  = (u16*)alloc((size_t)512 * 1024 * 2);       // 1.0 MB
    u16* xgT     = (u16*)alloc((size_t)2 * G4 * MTB * 2);     // 134.2 MB
    u16* h_all   = (u16*)alloc((size_t)MTB * 1024 * 2);       // 33.6 MB
    unsigned* flags = (unsigned*)alloc(2 * 4 * 64 * sizeof(unsigned));
    (void)ws_size;

    // ---- convert inputs to bf16 ----
    cvt_bf16<<<1024, 256, 0, stream>>>(x, x_bf, MTB * 512);
    cvt_bf16<<<256, 256, 0, stream>>>(wihf, wih_bf, G4 * 512);
    cvt_bf16<<<256, 256, 0, stream>>>(wihb, wih_bf + (size_t)G4 * 512, G4 * 512);
    cvt_bf16<<<256, 256, 0, stream>>>(whhf, whh_bf, G4 * 512);
    cvt_bf16<<<256, 256, 0, stream>>>(whhb, whh_bf + (size_t)G4 * 512, G4 * 512);
    cvt_bf16<<<128, 256, 0, stream>>>(fcw, fcw_bf, 512 * 1024);

    // ---- phase 1: xgT[d] = w_ih[d] @ x^T + (b_ih + b_hh), bf16 out, gate-major ----
    gemm_bt<true, true><<<dim3(MTB / 128, G4 / 128), 256, 0, stream>>>(
        wih_bf, x_bf, xgT, bihf, bhhf, G4, MTB, 512);
    gemm_bt<true, true><<<dim3(MTB / 128, G4 / 128), 256, 0, stream>>>(
        wih_bf + (size_t)G4 * 512, x_bf, xgT + (size_t)G4 * MTB, bihb, bhhb, G4, MTB, 512);

    // ---- phase 2: persistent recurrence, direction-fused, RMW flag publish ----
    hipMemsetAsync(flags, 0, 2 * 4 * 64 * sizeof(unsigned), stream);
    lstm_persist<<<64, 256, 0, stream>>>(whh_bf, xgT, h_all, flags);

    // ---- phase 3: out = h_all @ fc_w^T + fc_b, fp32 out ----
    gemm_bt<false, false><<<dim3(512 / 128, MTB / 128), 256, 0, stream>>>(
        h_all, fcw_bf, d_out, fcb, nullptr, MTB, 512, 1024);
}

// Round 11
// 1498.267 us; speedup vs baseline: 1.7631x; 1.7396x over previous
//
#include <hip/hip_runtime.h>

typedef unsigned short u16;
typedef unsigned int u32;
typedef unsigned long long u64;
typedef short v8s __attribute__((ext_vector_type(8)));
typedef float v4f __attribute__((ext_vector_type(4)));

// T=256, B=64, NIN=H=512, NOUT=512, 4H=2048, T*B=16384
#define TT 256
#define BB 64
#define HH 512
#define G4 2048
#define MTB 16384

static __device__ __forceinline__ float bf2f(u16 u) {
    u32 x = ((u32)u) << 16;
    union { u32 i; float f; } c; c.i = x; return c.f;
}
static __device__ __forceinline__ u16 f2bf(float f) {
    union { float f; u32 i; } c; c.f = f;
    u32 u = c.i;
    u += 0x7fffu + ((u >> 16) & 1u);   // RNE
    return (u16)(u >> 16);
}

__global__ __launch_bounds__(256) void cvt_bf16(const float* __restrict__ src,
                                                u16* __restrict__ dst, int n) {
    int i = blockIdx.x * blockDim.x + threadIdx.x;
    int stride = gridDim.x * blockDim.x;
    for (int j = i * 4; j < n; j += stride * 4) {
        float4 v = *reinterpret_cast<const float4*>(src + j);
        ushort4 o;
        o.x = f2bf(v.x); o.y = f2bf(v.y); o.z = f2bf(v.z); o.w = f2bf(v.w);
        *reinterpret_cast<ushort4*>(dst + j) = o;
    }
}

// C[M][N] = A[M][K] * B[N][K]^T (+ bias).  A,B bf16 K-contiguous; 128x128 tile, BK=64,
// 4 waves in 2x2, each wave 64x64 = 4x4 16x16x32 fragments. M,N,K multiples of 128 assumed.
template<bool OUT_BF16, bool BIAS_M>
__global__ __launch_bounds__(256) void gemm_bt(const u16* __restrict__ A,
                                               const u16* __restrict__ Bm,
                                               void* __restrict__ Cv,
                                               const float* __restrict__ bias1,
                                               const float* __restrict__ bias2,
                                               int M, int N, int K) {
    __shared__ u16 lds_a[128 * 64];
    __shared__ u16 lds_b[128 * 64];
    const int tid = threadIdx.x, lane = tid & 63;
    const int m0 = blockIdx.y * 128, n0 = blockIdx.x * 128;
    const int wid = tid >> 6, wm = wid >> 1, wn = wid & 1;
    v4f acc[4][4] = {};

    const int srow  = tid >> 3;        // 0..31: row within 32-row staging stripe
    const int skoff = (tid & 7) * 8;   // bf16 elements within 64-wide k
    const u16* Ag = A + (size_t)(m0 + srow) * K + skoff;
    const u16* Bg = Bm + (size_t)(n0 + srow) * K + skoff;
    u16* la = lds_a + srow * 64 + skoff;
    u16* lb = lds_b + srow * 64 + skoff;

    for (int k0 = 0; k0 < K; k0 += 64) {
        #pragma unroll
        for (int q = 0; q < 4; ++q) {
            *reinterpret_cast<v8s*>(la + q * 32 * 64) =
                *reinterpret_cast<const v8s*>(Ag + (size_t)q * 32 * K + k0);
            *reinterpret_cast<v8s*>(lb + q * 32 * 64) =
                *reinterpret_cast<const v8s*>(Bg + (size_t)q * 32 * K + k0);
        }
        __syncthreads();
        #pragma unroll
        for (int kk = 0; kk < 2; ++kk) {
            v8s af[4], bfr[4];
            #pragma unroll
            for (int i = 0; i < 4; ++i)
                af[i] = *reinterpret_cast<const v8s*>(
                    lds_a + (wm * 64 + i * 16 + (lane & 15)) * 64 + kk * 32 + (lane >> 4) * 8);
            #pragma unroll
            for (int i = 0; i < 4; ++i)
                bfr[i] = *reinterpret_cast<const v8s*>(
                    lds_b + (wn * 64 + i * 16 + (lane & 15)) * 64 + kk * 32 + (lane >> 4) * 8);
            #pragma unroll
            for (int i = 0; i < 4; ++i)
                #pragma unroll
                for (int j = 0; j < 4; ++j)
                    acc[i][j] = __builtin_amdgcn_mfma_f32_16x16x32_bf16(af[i], bfr[j], acc[i][j], 0, 0, 0);
        }
        __syncthreads();
    }
    // epilogue: D col = lane&15 (n), row = (lane>>4)*4 + reg (m)
    #pragma unroll
    for (int i = 0; i < 4; ++i) {
        #pragma unroll
        for (int j = 0; j < 4; ++j) {
            #pragma unroll
            for (int r = 0; r < 4; ++r) {
                int m = m0 + wm * 64 + i * 16 + (lane >> 4) * 4 + r;
                int n = n0 + wn * 64 + j * 16 + (lane & 15);
                float v = acc[i][j][r];
                if (BIAS_M) { v += bias1[m]; if (bias2) v += bias2[m]; }
                else        { v += bias1[n]; }
                if (OUT_BF16) ((u16*)Cv)[(size_t)m * N + n] = f2bf(v);
                else          ((float*)Cv)[(size_t)m * N + n] = v;
            }
        }
    }
}

static __device__ __forceinline__ float sigm(float x) { return 1.f / (1.f + __expf(-x)); }
static __device__ __forceinline__ float tanh_(float x) { return 2.f / (1.f + __expf(-2.f * x)) - 1.f; }

// Persistent bidirectional LSTM recurrence — R6 structure with MINIMAL sync traffic.
// Diagnosis: every sync variant lands at ~5us/step regardless of structure; R6's poll
// issues 32 uncoalescable atomic loads per wave per iteration x 256 spinning waves —
// hypothesis: this traffic congests the IC atomic path and inflates every latency in
// the serial chain. Change vs R6 (ONLY the sync fabric):
//   - one aggregated counter per (d,nf) group (8 total, 256B apart)
//   - producers: lane0 atomic_fetch_add(+1)  (near-memory RMW at the IC)
//   - consumers: all 64 lanes atomic-load the SAME address (TA merges same-address
//     reads into one transaction per wave); wait for >= 32*s.   => 32x less traffic.
// 64 blocks x 256 threads: blockIdx.x>>5 = dir d, &31 = cg. Wave nf owns batch rows
// b = nf*16..+15, all 4 gates, full K=512; w_hh slice (64 KB) LDS-resident as
// pre-swizzled fragments [G][kk][lane]*16B (conflict-free ds_read_b128).
__global__ __launch_bounds__(256, 2) void lstm_persist(
    const u16* __restrict__ w_hh,        // [2][2048][512]
    const u16* __restrict__ xgT,         // [2][2048][16384]  col = t*64+b
    u16* __restrict__ h_all,             // [256*64][1024]
    unsigned* __restrict__ flags)        // [8 groups * 64] counters, 256B apart
{
    __shared__ u16 wlds[4 * 16 * 64 * 8];    // [G][kk][lane][8 bf16] = 64 KB
    const int bx = blockIdx.x;
    const int d = bx >> 5, cg = bx & 31;
    const int lane = threadIdx.x & 63, nf = threadIdx.x >> 6;
    const int lrow = lane & 15, lk = lane >> 4;
    const int b = nf * 16 + lrow;        // this lane's batch column

    // ---- stage A fragments into LDS (once): wave nf fills gate G = nf ----
    {
        const int G = nf;
        const u16* wrow = w_hh + ((size_t)d * G4 + G * HH + cg * 16 + lrow) * HH + lk * 8;
        #pragma unroll
        for (int kk = 0; kk < 16; ++kk)
            *reinterpret_cast<v8s*>(&wlds[((G * 16 + kk) * 64 + lane) * 8]) =
                *reinterpret_cast<const v8s*>(wrow + kk * 32);
    }
    __syncthreads();

    float c[4] = {0.f, 0.f, 0.f, 0.f};
    float xg[4][4];
    unsigned* cnt = flags + (d * 4 + nf) * 64;   // this wave's group counter

    // xg for step 0
    {
        const int t0 = d ? (TT - 1) : 0;
        const u16* xgb = xgT + (size_t)d * G4 * MTB + (size_t)t0 * BB + b;
        #pragma unroll
        for (int G = 0; G < 4; ++G)
            #pragma unroll
            for (int r = 0; r < 4; ++r)
                xg[G][r] = bf2f(xgb[(size_t)(G * HH + cg * 16 + lk * 4 + r) * MTB]);
    }

    for (int s = 0; s < TT; ++s) {
        const int t = d ? (TT - 1 - s) : s;
        v4f acc[4] = {};
        if (s > 0) {
            // ---- prefetch kk=0..3 A-fragments from LDS (overlaps the poll) ----
            v8s af0[4][4];
            #pragma unroll
            for (int G = 0; G < 4; ++G)
                #pragma unroll
                for (int kk = 0; kk < 4; ++kk)
                    af0[G][kk] = *reinterpret_cast<const v8s*>(
                        &wlds[((G * 16 + kk) * 64 + lane) * 8]);
            // ---- wait: group counter reaches 32*s (one merged transaction/poll) ----
            const unsigned tgt = 32u * (unsigned)s;
            while (true) {
                unsigned fv = __hip_atomic_load(cnt, __ATOMIC_RELAXED,
                                                __HIP_MEMORY_SCOPE_AGENT);
                if (__all((int)(fv >= tgt))) break;
            }
            asm volatile("" ::: "memory");       // no load hoisting above the poll
            // ---- load h[tprev] B-fragments (16 x 16B, agent-coherent) ----
            const int tprev = d ? (t + 1) : (t - 1);
            const u16* hp = h_all + ((size_t)tprev * BB + b) * 1024 + d * HH + lk * 8;
            v8s bf_[16];
            #pragma unroll
            for (int kk = 0; kk < 16; ++kk) {
                union { u64 w[2]; v8s v; } u;
                const u16* p = hp + kk * 32;
                u.w[0] = __hip_atomic_load((const u64*)p,
                                           __ATOMIC_RELAXED, __HIP_MEMORY_SCOPE_AGENT);
                u.w[1] = __hip_atomic_load((const u64*)(p + 4),
                                           __ATOMIC_RELAXED, __HIP_MEMORY_SCOPE_AGENT);
                bf_[kk] = u.v;
            }
            // ---- MFMA: prefetched kk<4, then LDS-streamed kk=4..15 ----
            #pragma unroll
            for (int kk = 0; kk < 4; ++kk)
                #pragma unroll
                for (int G = 0; G < 4; ++G)
                    acc[G] = __builtin_amdgcn_mfma_f32_16x16x32_bf16(af0[G][kk], bf_[kk], acc[G], 0, 0, 0);
            #pragma unroll
            for (int kk = 4; kk < 16; ++kk)
                #pragma unroll
                for (int G = 0; G < 4; ++G) {
                    v8s af = *reinterpret_cast<const v8s*>(
                        &wlds[((G * 16 + kk) * 64 + lane) * 8]);
                    acc[G] = __builtin_amdgcn_mfma_f32_16x16x32_bf16(af, bf_[kk], acc[G], 0, 0, 0);
                }
        }
        // ---- gates + state update (all in this lane) ----
        ushort4 hout;
        #pragma unroll
        for (int r = 0; r < 4; ++r) {
            float pi = acc[0][r] + xg[0][r];
            float pf = acc[1][r] + xg[1][r];
            float pg = acc[2][r] + xg[2][r];
            float po = acc[3][r] + xg[3][r];
            float iv = sigm(pi), fv = sigm(pf), gv = tanh_(pg), ov = sigm(po);
            float cc = fv * c[r] + iv * gv;
            c[r] = cc;
            ((u16*)&hout)[r] = f2bf(ov * tanh_(cc));
        }
        // h[t][b][d*512 + cg*16 + lk*4 .. +3]  (8B agent store)
        union { ushort4 v; u64 q; } hu; hu.v = hout;
        __hip_atomic_store((u64*)(
                h_all + ((size_t)t * BB + b) * 1024 + d * HH + cg * 16 + lk * 4),
            hu.q, __ATOMIC_RELAXED, __HIP_MEMORY_SCOPE_AGENT);
        // drain this wave's h store, then publish via near-memory RMW
        asm volatile("s_waitcnt vmcnt(0)" ::: "memory");
        if (lane == 0)
            __hip_atomic_fetch_add(cnt, 1u, __ATOMIC_RELAXED, __HIP_MEMORY_SCOPE_AGENT);
        // ---- prefetch next step's xg (shadow overlaps the propagation window) ----
        if (s + 1 < TT) {
            const int tn = d ? (TT - 2 - s) : (s + 1);
            const u16* xgb = xgT + (size_t)d * G4 * MTB + (size_t)tn * BB + b;
            #pragma unroll
            for (int G = 0; G < 4; ++G)
                #pragma unroll
                for (int r = 0; r < 4; ++r)
                    xg[G][r] = bf2f(xgb[(size_t)(G * HH + cg * 16 + lk * 4 + r) * MTB]);
        }
    }
}

extern "C" void kernel_launch(void* const* d_in, const int* in_sizes, int n_in,
                              void* d_out, int out_size, void* d_ws, size_t ws_size,
                              hipStream_t stream) {
    const float* x    = (const float*)d_in[0];
    const float* wihf = (const float*)d_in[1];
    const float* whhf = (const float*)d_in[2];
    const float* bihf = (const float*)d_in[3];
    const float* bhhf = (const float*)d_in[4];
    const float* wihb = (const float*)d_in[5];
    const float* whhb = (const float*)d_in[6];
    const float* bihb = (const float*)d_in[7];
    const float* bhhb = (const float*)d_in[8];
    const float* fcw  = (const float*)d_in[9];
    const float* fcb  = (const float*)d_in[10];

    char* ws = (char*)d_ws;
    size_t off = 0;
    auto alloc = [&](size_t bytes) {
        off = (off + 255) & ~(size_t)255;
        char* p = ws + off; off += bytes; return p;
    };
    u16* x_bf    = (u16*)alloc((size_t)MTB * 512 * 2);        // 16.8 MB
    u16* wih_bf  = (u16*)alloc((size_t)2 * G4 * 512 * 2);     // 4.2 MB
    u16* whh_bf  = (u16*)alloc((size_t)2 * G4 * 512 * 2);     // 4.2 MB
    u16* fcw_bf  = (u16*)alloc((size_t)512 * 1024 * 2);       // 1.0 MB
    u16* xgT     = (u16*)alloc((size_t)2 * G4 * MTB * 2);     // 134.2 MB
    u16* h_all   = (u16*)alloc((size_t)MTB * 1024 * 2);       // 33.6 MB
    unsigned* flags = (unsigned*)alloc(8 * 64 * sizeof(unsigned));
    (void)ws_size;

    // ---- convert inputs to bf16 ----
    cvt_bf16<<<1024, 256, 0, stream>>>(x, x_bf, MTB * 512);
    cvt_bf16<<<256, 256, 0, stream>>>(wihf, wih_bf, G4 * 512);
    cvt_bf16<<<256, 256, 0, stream>>>(wihb, wih_bf + (size_t)G4 * 512, G4 * 512);
    cvt_bf16<<<256, 256, 0, stream>>>(whhf, whh_bf, G4 * 512);
    cvt_bf16<<<256, 256, 0, stream>>>(whhb, whh_bf + (size_t)G4 * 512, G4 * 512);
    cvt_bf16<<<128, 256, 0, stream>>>(fcw, fcw_bf, 512 * 1024);

    // ---- phase 1: xgT[d] = w_ih[d] @ x^T + (b_ih + b_hh), bf16 out, gate-major ----
    gemm_bt<true, true><<<dim3(MTB / 128, G4 / 128), 256, 0, stream>>>(
        wih_bf, x_bf, xgT, bihf, bhhf, G4, MTB, 512);
    gemm_bt<true, true><<<dim3(MTB / 128, G4 / 128), 256, 0, stream>>>(
        wih_bf + (size_t)G4 * 512, x_bf, xgT + (size_t)G4 * MTB, bihb, bhhb, G4, MTB, 512);

    // ---- phase 2: persistent recurrence, aggregated-counter sync ----
    hipMemsetAsync(flags, 0, 8 * 64 * sizeof(unsigned), stream);
    lstm_persist<<<64, 256, 0, stream>>>(whh_bf, xgT, h_all, flags);

    // ---- phase 3: out = h_all @ fc_w^T + fc_b, fp32 out ----
    gemm_bt<false, false><<<dim3(512 / 128, MTB / 128), 256, 0, stream>>>(
        h_all, fcw_bf, d_out, fcb, nullptr, MTB, 512, 1024);
}